// Round 11
// baseline (208.631 us; speedup 1.0000x reference)
//
#include <hip/hip_runtime.h>
#include <cmath>

#define WIN 11
#define HALO 5
#define IMG 512
#define NIMG 48
#define NPIX (16.0 * 3.0 * 512.0 * 512.0)
#define TROWS 74             /* 64 output rows + 2*5 halo rows staged in LDS */
#define NPART (8 * 8 * NIMG) /* 3072 per-block partials */

typedef _Float16 f16;
typedef _Float16 h2 __attribute__((ext_vector_type(2)));

struct GaussW { float w[WIN]; };

__device__ __forceinline__ unsigned pk2(float a, float b) {
    auto h = __builtin_amdgcn_cvt_pkrtz(a, b);   // __fp16 ext_vector(2)
    return __builtin_bit_cast(unsigned, h);
}
__device__ __forceinline__ h2 uph(unsigned u) {
    return __builtin_bit_cast(h2, u);
}

__global__ void __launch_bounds__(64) zero_kernel(float* out) {
    if (threadIdx.x == 0) out[0] = 0.f;
}

__global__ void __launch_bounds__(64) finish_kernel(float* out) {
    if (threadIdx.x == 0)
        out[0] = 1.0f - out[0] * (float)(1.0 / NPIX);
}

// ---------------- Fused SSIM: one block = 64x64 output tile -----------------
// Stage A: h-blur 74 rows x 64 cols of 4 fields {x, y, x^2+y^2, xy} -> LDS
// (uint4 per col-pair, 512 B/row). Stage B: v-blur 8 rows/thread from LDS
// (accumulate-by-input, one uint4 live), SSIM, block reduce, PLAIN partial
// store (R9 lesson: same-address atomics serialize ~14 ns each — that was
// the 176-232 us plateau of rounds 0-8).
__global__ void __launch_bounds__(256) ssim_fused(
        const float* __restrict__ xin, const float* __restrict__ yin,
        float* __restrict__ partial, float* __restrict__ out_atomic,
        int useAtomic, GaussW W) {
    __shared__ uint4 lds[TROWS][32];
    __shared__ float wsum[4];
    const int tid = threadIdx.x;
    const int bx = blockIdx.x, by = blockIdx.y, bz = blockIdx.z;
    const float* __restrict__ xb = xin + (size_t)bz * IMG * IMG;
    const float* __restrict__ yb = yin + (size_t)bz * IMG * IMG;
    const bool colfast = (bx >= 1 && bx <= 6);

    // ---- Stage A: 592 items = 74 rows x 8 col-groups (8 cols each)
    for (int i = tid; i < TROWS * 8; i += 256) {
        const int r  = i >> 3;
        const int cg = i & 7;
        const int gy  = by * 64 - HALO + r;
        const int gx0 = bx * 64 + cg * 8 - HALO;   // window cols gx0..gx0+17
        const bool rowok = ((unsigned)gy < IMG);
        const float* xr = xb + (size_t)gy * IMG;
        const float* yr = yb + (size_t)gy * IMG;

        float xv[18], yv[18];
        if (rowok && colfast) {
            // gx0+1 is 4-aligned: four aligned float4 runs cover [gx0+1, gx0+16]
            xv[0] = xr[gx0];  yv[0] = yr[gx0];
            #pragma unroll
            for (int q = 0; q < 4; ++q) {
                float4 a = *(const float4*)(xr + gx0 + 1 + 4*q);
                float4 b = *(const float4*)(yr + gx0 + 1 + 4*q);
                xv[1+4*q] = a.x; xv[2+4*q] = a.y; xv[3+4*q] = a.z; xv[4+4*q] = a.w;
                yv[1+4*q] = b.x; yv[2+4*q] = b.y; yv[3+4*q] = b.z; yv[4+4*q] = b.w;
            }
            xv[17] = xr[gx0 + 17];  yv[17] = yr[gx0 + 17];
        } else {
            #pragma unroll
            for (int j = 0; j < 18; ++j) {
                int gx = gx0 + j;
                bool ok = rowok && ((unsigned)gx < IMG);
                xv[j] = ok ? xr[gx] : 0.f;
                yv[j] = ok ? yr[gx] : 0.f;
            }
        }

        float ax[8]  = {0,0,0,0,0,0,0,0}, ay[8]  = {0,0,0,0,0,0,0,0};
        float as_[8] = {0,0,0,0,0,0,0,0}, axy[8] = {0,0,0,0,0,0,0,0};
        #pragma unroll
        for (int j = 0; j < 18; ++j) {
            float xs = xv[j], ys = yv[j];
            float xy = xs * ys;
            float ss = fmaf(xs, xs, ys * ys);     // x^2 + y^2 as one field
            #pragma unroll
            for (int o = 0; o < 8; ++o) {
                int k = j - o;
                if (k >= 0 && k < WIN) {
                    float wk = W.w[k];
                    ax[o]  += wk * xs;
                    ay[o]  += wk * ys;
                    as_[o] += wk * ss;
                    axy[o] += wk * xy;
                }
            }
        }
        #pragma unroll
        for (int p = 0; p < 4; ++p) {
            uint4 u;
            u.x = pk2(ax[2*p],  ax[2*p+1]);
            u.y = pk2(ay[2*p],  ay[2*p+1]);
            u.z = pk2(as_[2*p], as_[2*p+1]);
            u.w = pk2(axy[2*p], axy[2*p+1]);
            lds[r][cg * 4 + p] = u;
        }
    }
    __syncthreads();

    // ---- Stage B: thread = col-pair (tid&31) x 8 output rows (8*(tid>>5)..+7)
    const int cp = tid & 31;
    const int rg = tid >> 5;
    const h2 z = (h2){(f16)0, (f16)0};
    h2 a0[8], a1[8], a2[8], a3[8];
    #pragma unroll
    for (int o = 0; o < 8; ++o) { a0[o]=z; a1[o]=z; a2[o]=z; a3[o]=z; }
    h2 w2[WIN];
    #pragma unroll
    for (int k = 0; k < WIN; ++k) { f16 wk = (f16)W.w[k]; w2[k] = (h2){wk, wk}; }

    #pragma unroll
    for (int j = 0; j < 18; ++j) {
        uint4 u = lds[8 * rg + j][cp];
        h2 v0 = uph(u.x), v1 = uph(u.y), v2 = uph(u.z), v3 = uph(u.w);
        #pragma unroll
        for (int o = 0; o < 8; ++o) {
            int k = j - o;
            if (k >= 0 && k < WIN) {
                h2 wk = w2[k];
                a0[o] += wk * v0;
                a1[o] += wk * v1;
                a2[o] += wk * v2;
                a3[o] += wk * v3;
            }
        }
    }

    const float C1 = 0.01f * 0.01f;
    const float C2 = 0.03f * 0.03f;
    float local = 0.f;
    #pragma unroll
    for (int o = 0; o < 8; ++o) {
        #pragma unroll
        for (int h = 0; h < 2; ++h) {
            float mux = (float)a0[o][h];
            float muy = (float)a1[o][h];
            float es  = (float)a2[o][h];          // E[x^2 + y^2]
            float exy = (float)a3[o][h];
            float mux2 = mux * mux, muy2 = muy * muy, muxy = mux * muy;
            float num = (2.f * muxy + C1) * (2.f * (exy - muxy) + C2);
            float den = (mux2 + muy2 + C1) * ((es - mux2 - muy2) + C2);
            local += num * __builtin_amdgcn_rcpf(den + 1e-8f);
        }
    }

    #pragma unroll
    for (int off = 32; off > 0; off >>= 1)
        local += __shfl_down(local, off, 64);
    if ((tid & 63) == 0) wsum[tid >> 6] = local;
    __syncthreads();
    if (tid == 0) {
        float s = wsum[0] + wsum[1] + wsum[2] + wsum[3];
        if (useAtomic) atomicAdd(out_atomic, s);
        else partial[bz * 64 + by * 8 + bx] = s;
    }
}

// ---------------- Final reduce: 3072 partials -> out[0], one block ----------
__global__ void __launch_bounds__(256) reduce_kernel(
        const float* __restrict__ partial, float* __restrict__ out) {
    __shared__ float wsum[4];
    const int tid = threadIdx.x;
    float s = 0.f;
    for (int i = tid; i < NPART; i += 256) s += partial[i];
    #pragma unroll
    for (int off = 32; off > 0; off >>= 1)
        s += __shfl_down(s, off, 64);
    if ((tid & 63) == 0) wsum[tid >> 6] = s;
    __syncthreads();
    if (tid == 0)
        out[0] = 1.0f - (wsum[0] + wsum[1] + wsum[2] + wsum[3]) * (float)(1.0 / NPIX);
}

extern "C" void kernel_launch(void* const* d_in, const int* in_sizes, int n_in,
                              void* d_out, int out_size, void* d_ws, size_t ws_size,
                              hipStream_t stream) {
    const float* x = (const float*)d_in[0];
    const float* y = (const float*)d_in[1];
    float* out = (float*)d_out;

    GaussW gw;
    double g[WIN], s = 0.0;
    for (int i = 0; i < WIN; ++i) {
        double d = (double)(i - WIN / 2);
        g[i] = exp(-(d * d) / (2.0 * 1.5 * 1.5));
        s += g[i];
    }
    for (int i = 0; i < WIN; ++i) gw.w[i] = (float)(g[i] / s);

    if (ws_size >= (size_t)NPART * sizeof(float)) {
        float* partial = (float*)d_ws;
        hipLaunchKernelGGL(ssim_fused, dim3(8, 8, NIMG), dim3(256), 0, stream,
                           x, y, partial, out, 0, gw);
        hipLaunchKernelGGL(reduce_kernel, dim3(1), dim3(256), 0, stream, partial, out);
    } else {
        hipLaunchKernelGGL(zero_kernel, dim3(1), dim3(64), 0, stream, out);
        hipLaunchKernelGGL(ssim_fused, dim3(8, 8, NIMG), dim3(256), 0, stream,
                           x, y, (float*)nullptr, out, 1, gw);
        hipLaunchKernelGGL(finish_kernel, dim3(1), dim3(64), 0, stream, out);
    }
}